// Round 3
// baseline (69450.354 us; speedup 1.0000x reference)
//
#include <hip/hip_runtime.h>
#include <math.h>

#define BLOCK 64

namespace {

constexpr int   NT_   = 8;
constexpr int   HID_  = 64;
constexpr int   NB_   = 12;
constexpr int   OD_   = 74;      // 2*NB*3 + 2
constexpr float TB_   = 5.0f;
constexpr float MINW_ = 0.001f;
constexpr float MINH_ = 0.001f;
constexpr float MIND_ = 0.001f;
constexpr float LOGZ_ = -2.7568155996140185f;  // -0.5*3*log(2*pi)

// LDS slot map (per-thread column, 64 slots x BLOCK threads, [slot][tid]):
//   GEMM phases:   slots 0..63  = staging for layer outputs
//   spline phase:  slots 0..36  = params (uw 0..11, uh 12..23, ud 24..36)
//                  slots 37..49 = cw[0..12]   (KW = 37)
//                  slots 50..62 = ch[0..12]   (KH = 50)
constexpr int KW_ = 37;
constexpr int KH_ = 50;

__device__ __forceinline__ float softplus_(float v) {
    return fmaxf(v, 0.0f) + log1pf(__expf(-fabsf(v)));
}

// Rational-quadratic spline; Tb = &T_sh[tid], params at Tb[q*BLOCK].
__device__ __forceinline__ void rq_spline_(float* Tb, float xr,
                                           float& y_out, float& lad_out) {
    float mw = -1e30f, mh = -1e30f;
#pragma unroll
    for (int q = 0; q < NB_; ++q) mw = fmaxf(mw, Tb[q * BLOCK]);
#pragma unroll
    for (int q = 0; q < NB_; ++q) mh = fmaxf(mh, Tb[(NB_ + q) * BLOCK]);

    float ew[NB_], eh[NB_];
    float sw = 0.0f, sh = 0.0f;
#pragma unroll
    for (int q = 0; q < NB_; ++q) { ew[q] = __expf(Tb[q * BLOCK] - mw);          sw += ew[q]; }
#pragma unroll
    for (int q = 0; q < NB_; ++q) { eh[q] = __expf(Tb[(NB_ + q) * BLOCK] - mh);  sh += eh[q]; }

    const float iw = (1.0f - MINW_ * (float)NB_) / sw;
    const float ih = (1.0f - MINH_ * (float)NB_) / sh;

    const float xc = fminf(fmaxf(xr, -TB_), TB_);

    // build knot arrays in LDS, count bin on the fly
    Tb[KW_ * BLOCK] = -TB_;
    Tb[KH_ * BLOCK] = -TB_;
    float rw = 0.0f, rh = 0.0f;
    int bi = 0;
#pragma unroll
    for (int q = 0; q < NB_; ++q) {
        rw += MINW_ + ew[q] * iw;
        rh += MINH_ + eh[q] * ih;
        const float cwv = (q == NB_ - 1) ? TB_ : fmaf(2.0f * TB_, rw, -TB_);
        const float chv = (q == NB_ - 1) ? TB_ : fmaf(2.0f * TB_, rh, -TB_);
        Tb[(KW_ + 1 + q) * BLOCK] = cwv;
        Tb[(KH_ + 1 + q) * BLOCK] = chv;
        if (q < NB_ - 1) bi += (xc >= cwv) ? 1 : 0;
    }

    // dynamic-index gathers (bank = tid%32 regardless of bi -> 2-way, free)
    const float in_cw = Tb[(KW_ + bi) * BLOCK];
    const float cwn   = Tb[(KW_ + 1 + bi) * BLOCK];
    const float in_ch = Tb[(KH_ + bi) * BLOCK];
    const float chn   = Tb[(KH_ + 1 + bi) * BLOCK];
    // padded derivs: d[0]=1 exactly; d_k = d[bi], d_k1 = d[bi+1]
    const float d_k  = (bi == 0) ? 1.0f : (MIND_ + softplus_(Tb[(23 + bi) * BLOCK]));
    const float d_k1 = MIND_ + softplus_(Tb[(24 + bi) * BLOCK]);

    const float in_w  = cwn - in_cw;
    const float in_h  = chn - in_ch;
    const float delta = in_h / in_w;
    const float theta = (xc - in_cw) / in_w;
    const float omt   = 1.0f - theta;
    const float t1m   = theta * omt;
    const float num   = in_h * (delta * theta * theta + d_k * t1m);
    const float den   = delta + (d_k + d_k1 - 2.0f * delta) * t1m;
    const float y     = in_ch + num / den;
    const float dnum  = delta * delta * (d_k1 * theta * theta + 2.0f * delta * t1m + d_k * omt * omt);
    const float lad   = __logf(dnum) - 2.0f * __logf(den);

    const bool inside = (xr >= -TB_) && (xr <= TB_);
    y_out   = inside ? y   : xr;
    lad_out = inside ? lad : 0.0f;
}

// out[o] = b[o] + sum_k in[k]*W[o][k]  -> Tb[o*BLOCK], optional fused relu.
// Wv/bv MUST be derived from a divergent (VGPR) base so loads go through
// VMEM (vmcnt, in-order, pipelineable) instead of SMEM (lgkmcnt full-drain).
template <int NOUT, bool RELU>
__device__ __forceinline__ void dense_v(const float (&in)[HID_],
                                        const float* __restrict__ Wv,
                                        const float* __restrict__ bv,
                                        float* Tb) {
#pragma unroll 2
    for (int o = 0; o < NOUT; ++o) {
        const float4* w4 = (const float4*)(Wv + o * HID_);
        float4 wq[16];
#pragma unroll
        for (int c = 0; c < 16; ++c) wq[c] = w4[c];
        float a0 = bv[o], a1 = 0.0f, a2 = 0.0f, a3 = 0.0f;
#pragma unroll
        for (int c = 0; c < 16; ++c) {
            a0 = fmaf(in[4 * c + 0], wq[c].x, a0);
            a1 = fmaf(in[4 * c + 1], wq[c].y, a1);
            a2 = fmaf(in[4 * c + 2], wq[c].z, a2);
            a3 = fmaf(in[4 * c + 3], wq[c].w, a3);
        }
        const float v = (a0 + a1) + (a2 + a3);
        Tb[o * BLOCK] = RELU ? fmaxf(v, 0.0f) : v;
    }
}

__global__ __launch_bounds__(BLOCK, 2) void nsf_kernel(
    const float* __restrict__ x,
    const float* __restrict__ W_in,  const float* __restrict__ b_in,
    const float* __restrict__ W_blk, const float* __restrict__ b_blk,
    const float* __restrict__ W_out, const float* __restrict__ b_out,
    float* __restrict__ out, int n)
{
    __shared__ float T_sh[64 * BLOCK];   // 16 KB: per-thread 64-slot column

    const int tid = threadIdx.x;
    const int idx = blockIdx.x * BLOCK + tid;
    if (idx >= n) return;

    // Opaque divergent zero: forces all weight addresses into VGPRs so the
    // compiler emits global_load_dwordx4 (VMEM/vmcnt) instead of s_load.
    int vz;
    asm volatile("v_mov_b32 %0, 0" : "=v"(vz));

    float* Tb = &T_sh[tid];

    float z0 = x[3 * idx + 0];
    float z1 = x[3 * idx + 1];
    float z2 = x[3 * idx + 2];
    float lad_total = 0.0f;

    float h[HID_];
    float r[HID_];

#pragma unroll 1
    for (int i = 0; i < NT_; ++i) {
        // z[:, ::-1]: ident = old z2, tr = (old z1, old z0)
        const float ident = z2;
        const float tr0   = z1;
        const float tr1   = z0;

        const float4* Wi4 = (const float4*)(W_in + i * HID_ + vz);
        const float4* Bi4 = (const float4*)(b_in + i * HID_ + vz);
#pragma unroll
        for (int c = 0; c < 16; ++c) {
            const float4 wi = Wi4[c];
            const float4 bi = Bi4[c];
            h[4 * c + 0] = fmaf(ident, wi.x, bi.x);
            h[4 * c + 1] = fmaf(ident, wi.y, bi.y);
            h[4 * c + 2] = fmaf(ident, wi.z, bi.z);
            h[4 * c + 3] = fmaf(ident, wi.w, bi.w);
        }

#pragma unroll 1
        for (int j = 0; j < 2; ++j) {
            const float* WA = W_blk + (size_t)(i * 4 + 2 * j) * HID_ * HID_ + vz;
            const float* bA = b_blk + (i * 4 + 2 * j) * HID_ + vz;
            const float* WB = WA + HID_ * HID_;
            const float* bB = bA + HID_;

#pragma unroll
            for (int k = 0; k < HID_; ++k) r[k] = fmaxf(h[k], 0.0f);

            dense_v<HID_, true>(r, WA, bA, Tb);    // relu(t1) -> slots 0..63

#pragma unroll
            for (int k = 0; k < HID_; ++k) r[k] = Tb[k * BLOCK];

            dense_v<HID_, false>(r, WB, bB, Tb);   // t2 -> slots 0..63

#pragma unroll
            for (int k = 0; k < HID_; ++k) h[k] += Tb[k * BLOCK];   // residual
        }

        // out head in two 37-wide halves; spline consumes each half in place
        const float* Wo = W_out + (size_t)i * OD_ * HID_ + vz;
        const float* bo = b_out + i * OD_ + vz;

        float y0, l0, y1, l1;
        dense_v<37, false>(h, Wo, bo, Tb);                     // params[0..37)
        rq_spline_(Tb, tr0, y0, l0);
        dense_v<37, false>(h, Wo + 37 * HID_, bo + 37, Tb);    // params[37..74)
        rq_spline_(Tb, tr1, y1, l1);

        lad_total += l0 + l1;

        z0 = ident;
        z1 = y0;
        z2 = y1;
    }

    out[idx] = -0.5f * (z0 * z0 + z1 * z1 + z2 * z2) + LOGZ_ + lad_total;
}

}  // namespace

extern "C" void kernel_launch(void* const* d_in, const int* in_sizes, int n_in,
                              void* d_out, int out_size, void* d_ws, size_t ws_size,
                              hipStream_t stream) {
    const float* x     = (const float*)d_in[0];
    const float* W_in  = (const float*)d_in[1];
    const float* b_in  = (const float*)d_in[2];
    const float* W_blk = (const float*)d_in[3];
    const float* b_blk = (const float*)d_in[4];
    const float* W_out = (const float*)d_in[5];
    const float* b_out = (const float*)d_in[6];
    float* out = (float*)d_out;

    const int n = in_sizes[0] / 3;
    const int grid = (n + BLOCK - 1) / BLOCK;
    nsf_kernel<<<grid, BLOCK, 0, stream>>>(x, W_in, b_in, W_blk, b_blk,
                                           W_out, b_out, out, n);
}

// Round 4
// 9380.871 us; speedup vs baseline: 7.4034x; 7.4034x over previous
//
#include <hip/hip_runtime.h>
#include <math.h>

#define BLOCK 64

namespace {

constexpr int   NT_   = 8;
constexpr int   HID_  = 64;
constexpr int   NB_   = 12;
constexpr int   OD_   = 74;      // 2*NB*3 + 2
constexpr float TB_   = 5.0f;
constexpr float MINW_ = 0.001f;
constexpr float MINH_ = 0.001f;
constexpr float MIND_ = 0.001f;
constexpr float LOGZ_ = -2.7568155996140185f;  // -0.5*3*log(2*pi)

// d_ws layout (floats): WT_blk[32][64][64] (k-major), then WT_out[8][64][74]
constexpr int WT_BLK_ELEMS = 32 * 64 * 64;   // 131072
constexpr int WT_OUT_ELEMS = 8 * 64 * 74;    // 37888

__device__ __forceinline__ float softplus_(float v) {
    return fmaxf(v, 0.0f) + log1pf(__expf(-fabsf(v)));
}

// Rational-quadratic spline, params fully in registers (static indexing).
// p[0..11]=uw, p[12..23]=uh, p[24..36]=ud.  (round-1 verified math)
__device__ __forceinline__ void rq_spline_reg(const float (&p)[37], float xr,
                                              float& y_out, float& lad_out) {
    float mw = -1e30f, mh = -1e30f;
#pragma unroll
    for (int q = 0; q < NB_; ++q) { mw = fmaxf(mw, p[q]); mh = fmaxf(mh, p[NB_ + q]); }

    float ew[NB_], eh[NB_];
    float sw = 0.0f, sh = 0.0f;
#pragma unroll
    for (int q = 0; q < NB_; ++q) { ew[q] = __expf(p[q] - mw);        sw += ew[q]; }
#pragma unroll
    for (int q = 0; q < NB_; ++q) { eh[q] = __expf(p[NB_ + q] - mh);  sh += eh[q]; }

    const float iw = (1.0f - MINW_ * (float)NB_) / sw;
    const float ih = (1.0f - MINH_ * (float)NB_) / sh;

    float cw[NB_ + 1], ch[NB_ + 1];
    cw[0] = -TB_; ch[0] = -TB_;
    float rw = 0.0f, rh = 0.0f;
#pragma unroll
    for (int q = 0; q < NB_; ++q) {
        rw += MINW_ + ew[q] * iw;
        rh += MINH_ + eh[q] * ih;
        cw[q + 1] = fmaf(2.0f * TB_, rw, -TB_);
        ch[q + 1] = fmaf(2.0f * TB_, rh, -TB_);
    }
    cw[NB_] = TB_;   // forced exact endpoints
    ch[NB_] = TB_;

    const float xc = fminf(fmaxf(xr, -TB_), TB_);

    int bi = 0;
#pragma unroll
    for (int q = 1; q <= NB_ - 1; ++q) bi += (xc >= cw[q]) ? 1 : 0;

    // gather for bin bi via unrolled selects (no dynamic reg indexing)
    float in_cw = cw[0], cwn = cw[1], in_ch = ch[0], chn = ch[1];
    float udm1 = 0.0f, ud0 = p[24];
#pragma unroll
    for (int q = 1; q < NB_; ++q) {
        const bool s = (bi == q);
        in_cw = s ? cw[q]       : in_cw;
        cwn   = s ? cw[q + 1]   : cwn;
        in_ch = s ? ch[q]       : in_ch;
        chn   = s ? ch[q + 1]   : chn;
        udm1  = s ? p[24 + q - 1] : udm1;
        ud0   = s ? p[24 + q]     : ud0;
    }
    const float in_w = cwn - in_cw;
    const float in_h = chn - in_ch;
    // padded derivs: d[0]=1 exactly
    const float d_k  = (bi == 0) ? 1.0f : (MIND_ + softplus_(udm1));
    const float d_k1 = MIND_ + softplus_(ud0);

    const float delta = in_h / in_w;
    const float theta = (xc - in_cw) / in_w;
    const float omt   = 1.0f - theta;
    const float t1m   = theta * omt;
    const float num   = in_h * (delta * theta * theta + d_k * t1m);
    const float den   = delta + (d_k + d_k1 - 2.0f * delta) * t1m;
    const float y     = in_ch + num / den;
    const float dnum  = delta * delta * (d_k1 * theta * theta + 2.0f * delta * t1m + d_k * omt * omt);
    const float lad   = __logf(dnum) - 2.0f * __logf(den);

    const bool inside = (xr >= -TB_) && (xr <= TB_);
    y_out   = inside ? y   : xr;
    lad_out = inside ? lad : 0.0f;
}

// Pre-pass: transpose W_blk (32 x 64x64) and W_out (8 x 74x64) into d_ws.
__global__ __launch_bounds__(256) void transpose_k(const float* __restrict__ Wb,
                                                   const float* __restrict__ Wo,
                                                   float* __restrict__ wt) {
    const int t = blockIdx.x * 256 + threadIdx.x;
    if (t < WT_BLK_ELEMS) {
        const int l = t >> 12, k = (t >> 6) & 63, o = t & 63;
        wt[t] = Wb[l * 4096 + o * 64 + k];           // WT[l][k][o] = W[l][o][k]
    } else if (t < WT_BLK_ELEMS + WT_OUT_ELEMS) {
        const int t2 = t - WT_BLK_ELEMS;
        const int i  = t2 / (64 * 74);
        const int r  = t2 - i * (64 * 74);
        const int k  = r / 74;
        const int o  = r - k * 74;
        wt[t] = Wo[(i * 74 + o) * 64 + k];           // WTo[i][k][o] = Wo[i][o][k]
    }
}

__global__ __launch_bounds__(BLOCK, 3) void nsf_kernel(
    const float* __restrict__ x,
    const float* __restrict__ W_in,  const float* __restrict__ b_in,
    const float* __restrict__ b_blk, const float* __restrict__ b_out,
    const float* __restrict__ wt,    // transposed weights in d_ws
    float* __restrict__ out, int n)
{
    __shared__ float slab[64 * BLOCK];   // 16 KB; [slot][tid], thread-private columns

    const int tid = threadIdx.x;
    const int idx = blockIdx.x * BLOCK + tid;
    if (idx >= n) return;

    float z0 = x[3 * idx + 0];
    float z1 = x[3 * idx + 1];
    float z2 = x[3 * idx + 2];
    float lad_total = 0.0f;

    float h[HID_];

#pragma unroll 1
    for (int i = 0; i < NT_; ++i) {
        // z[:, ::-1]: ident = old z2, tr = (old z1, old z0)
        const float ident = z2;
        const float tr0   = z1;
        const float tr1   = z0;

        const float* Wi = W_in + i * HID_;   // uniform -> s_load
        const float* bi = b_in + i * HID_;
#pragma unroll
        for (int o = 0; o < HID_; ++o) h[o] = fmaf(ident, Wi[o], bi[o]);

#pragma unroll 1
        for (int j = 0; j < 2; ++j) {
            const float* WT_A = wt + (size_t)(i * 4 + 2 * j) * 4096;
            const float* WT_B = WT_A + 4096;
            const float* bA   = b_blk + (i * 4 + 2 * j) * HID_;
            const float* bB   = bA + HID_;

            // ---- dense A: t1 = bA + WA^T-rows . relu(h), k-outer ----
            float t1[HID_];
#pragma unroll
            for (int o = 0; o < HID_; ++o) t1[o] = bA[o];
#pragma unroll
            for (int k = 0; k < HID_; ++k) slab[k * BLOCK + tid] = h[k];
#pragma unroll 1
            for (int k = 0; k < HID_; ++k) {
                const float rk = fmaxf(slab[k * BLOCK + tid], 0.0f);
                const float* w = WT_A + k * 64;   // uniform row -> SGPRs
#pragma unroll
                for (int o = 0; o < HID_; ++o) t1[o] = fmaf(rk, w[o], t1[o]);
            }

            // ---- dense B + residual: h += bB + WB^T-rows . relu(t1) ----
#pragma unroll
            for (int k = 0; k < HID_; ++k) slab[k * BLOCK + tid] = fmaxf(t1[k], 0.0f);
#pragma unroll
            for (int o = 0; o < HID_; ++o) h[o] += bB[o];
#pragma unroll 1
            for (int k = 0; k < HID_; ++k) {
                const float rk = slab[k * BLOCK + tid];
                const float* w = WT_B + k * 64;
#pragma unroll
                for (int o = 0; o < HID_; ++o) h[o] = fmaf(rk, w[o], h[o]);
            }
        }

        // ---- output head: params = bo + Wo^T-rows . h (no relu), k-outer ----
        const float* WT_O = wt + WT_BLK_ELEMS + (size_t)i * 64 * 74;
        const float* bo   = b_out + i * OD_;

        float pa[37], pb[37];
#pragma unroll
        for (int o = 0; o < 37; ++o) pa[o] = bo[o];
#pragma unroll
        for (int o = 0; o < 37; ++o) pb[o] = bo[37 + o];
#pragma unroll
        for (int k = 0; k < HID_; ++k) slab[k * BLOCK + tid] = h[k];
#pragma unroll 1
        for (int k = 0; k < HID_; ++k) {
            const float hk = slab[k * BLOCK + tid];
            const float* w = WT_O + k * 74;
#pragma unroll
            for (int o = 0; o < 37; ++o) pa[o] = fmaf(hk, w[o], pa[o]);
#pragma unroll
            for (int o = 0; o < 37; ++o) pb[o] = fmaf(hk, w[37 + o], pb[o]);
        }

        float y0, l0, y1, l1;
        rq_spline_reg(pa, tr0, y0, l0);
        rq_spline_reg(pb, tr1, y1, l1);
        lad_total += l0 + l1;

        z0 = ident;
        z1 = y0;
        z2 = y1;
    }

    out[idx] = -0.5f * (z0 * z0 + z1 * z1 + z2 * z2) + LOGZ_ + lad_total;
}

}  // namespace

extern "C" void kernel_launch(void* const* d_in, const int* in_sizes, int n_in,
                              void* d_out, int out_size, void* d_ws, size_t ws_size,
                              hipStream_t stream) {
    const float* x     = (const float*)d_in[0];
    const float* W_in  = (const float*)d_in[1];
    const float* b_in  = (const float*)d_in[2];
    const float* W_blk = (const float*)d_in[3];
    const float* b_blk = (const float*)d_in[4];
    const float* W_out = (const float*)d_in[5];
    const float* b_out = (const float*)d_in[6];
    float* out = (float*)d_out;
    float* wt  = (float*)d_ws;   // needs 660 KB; harness scratch is larger

    // 1) transpose weights into workspace (every call; ws is re-poisoned)
    const int tot = WT_BLK_ELEMS + WT_OUT_ELEMS;           // 168960
    transpose_k<<<(tot + 255) / 256, 256, 0, stream>>>(W_blk, W_out, wt);

    // 2) main fused flow kernel
    const int n = in_sizes[0] / 3;
    const int grid = (n + BLOCK - 1) / BLOCK;
    nsf_kernel<<<grid, BLOCK, 0, stream>>>(x, W_in, b_in, b_blk, b_out,
                                           wt, out, n);
}

// Round 5
// 8595.309 us; speedup vs baseline: 8.0800x; 1.0914x over previous
//
#include <hip/hip_runtime.h>
#include <math.h>

#define BLOCK 64

namespace {

constexpr int   NT_   = 8;
constexpr int   HID_  = 64;
constexpr int   NB_   = 12;
constexpr int   OD_   = 74;      // 2*NB*3 + 2
constexpr float TB_   = 5.0f;
constexpr float MINW_ = 0.001f;
constexpr float MINH_ = 0.001f;
constexpr float MIND_ = 0.001f;
constexpr float LOGZ_ = -2.7568155996140185f;  // -0.5*3*log(2*pi)

// d_ws layout (floats):
//   WT_blk[32][64][64]        k-major dense tiles          (131072 floats)
//   WT_out[8][2][64][40]      k-major head halves, padded  (40960 floats)
constexpr int WT_BLK_ELEMS = 32 * 64 * 64;        // 131072
constexpr int WT_OUT_ELEMS = 8 * 2 * 64 * 40;     // 40960

__device__ __forceinline__ float softplus_(float v) {
    return fmaxf(v, 0.0f) + log1pf(__expf(-fabsf(v)));
}

// Rational-quadratic spline, params fully in registers (round-4 verified).
// p[0..11]=uw, p[12..23]=uh, p[24..36]=ud.
__device__ __forceinline__ void rq_spline_reg(const float (&p)[37], float xr,
                                              float& y_out, float& lad_out) {
    float mw = -1e30f, mh = -1e30f;
#pragma unroll
    for (int q = 0; q < NB_; ++q) { mw = fmaxf(mw, p[q]); mh = fmaxf(mh, p[NB_ + q]); }

    float ew[NB_], eh[NB_];
    float sw = 0.0f, sh = 0.0f;
#pragma unroll
    for (int q = 0; q < NB_; ++q) { ew[q] = __expf(p[q] - mw);        sw += ew[q]; }
#pragma unroll
    for (int q = 0; q < NB_; ++q) { eh[q] = __expf(p[NB_ + q] - mh);  sh += eh[q]; }

    const float iw = (1.0f - MINW_ * (float)NB_) / sw;
    const float ih = (1.0f - MINH_ * (float)NB_) / sh;

    float cw[NB_ + 1], ch[NB_ + 1];
    cw[0] = -TB_; ch[0] = -TB_;
    float rw = 0.0f, rh = 0.0f;
#pragma unroll
    for (int q = 0; q < NB_; ++q) {
        rw += MINW_ + ew[q] * iw;
        rh += MINH_ + eh[q] * ih;
        cw[q + 1] = fmaf(2.0f * TB_, rw, -TB_);
        ch[q + 1] = fmaf(2.0f * TB_, rh, -TB_);
    }
    cw[NB_] = TB_;
    ch[NB_] = TB_;

    const float xc = fminf(fmaxf(xr, -TB_), TB_);

    int bi = 0;
#pragma unroll
    for (int q = 1; q <= NB_ - 1; ++q) bi += (xc >= cw[q]) ? 1 : 0;

    float in_cw = cw[0], cwn = cw[1], in_ch = ch[0], chn = ch[1];
    float udm1 = 0.0f, ud0 = p[24];
#pragma unroll
    for (int q = 1; q < NB_; ++q) {
        const bool s = (bi == q);
        in_cw = s ? cw[q]         : in_cw;
        cwn   = s ? cw[q + 1]     : cwn;
        in_ch = s ? ch[q]         : in_ch;
        chn   = s ? ch[q + 1]     : chn;
        udm1  = s ? p[24 + q - 1] : udm1;
        ud0   = s ? p[24 + q]     : ud0;
    }
    const float in_w = cwn - in_cw;
    const float in_h = chn - in_ch;
    const float d_k  = (bi == 0) ? 1.0f : (MIND_ + softplus_(udm1));
    const float d_k1 = MIND_ + softplus_(ud0);

    const float delta = in_h / in_w;
    const float theta = (xc - in_cw) / in_w;
    const float omt   = 1.0f - theta;
    const float t1m   = theta * omt;
    const float num   = in_h * (delta * theta * theta + d_k * t1m);
    const float den   = delta + (d_k + d_k1 - 2.0f * delta) * t1m;
    const float y     = in_ch + num / den;
    const float dnum  = delta * delta * (d_k1 * theta * theta + 2.0f * delta * t1m + d_k * omt * omt);
    const float lad   = __logf(dnum) - 2.0f * __logf(den);

    const bool inside = (xr >= -TB_) && (xr <= TB_);
    y_out   = inside ? y   : xr;
    lad_out = inside ? lad : 0.0f;
}

// Pre-pass: k-major transposes into d_ws (dense + padded head halves).
__global__ __launch_bounds__(256) void transpose_k(const float* __restrict__ Wb,
                                                   const float* __restrict__ Wo,
                                                   float* __restrict__ wt) {
    const int t = blockIdx.x * 256 + threadIdx.x;
    if (t < WT_BLK_ELEMS) {
        const int l = t >> 12, k = (t >> 6) & 63, o = t & 63;
        wt[t] = Wb[l * 4096 + o * 64 + k];                 // WT[l][k][o]
    } else if (t < WT_BLK_ELEMS + WT_OUT_ELEMS) {
        const int t2   = t - WT_BLK_ELEMS;
        const int i    = t2 / 5120;
        const int r    = t2 - i * 5120;
        const int half = r / 2560;
        const int rr   = r - half * 2560;
        const int k    = rr / 40;
        const int c    = rr - k * 40;
        wt[t] = (c < 37) ? Wo[(i * 74 + half * 37 + c) * 64 + k] : 0.0f;
    }
}

// Stage N4 float4s from global (L2-hot) into LDS; lane l copies strided.
template <int N4>
__device__ __forceinline__ void stage_(const float4* __restrict__ src,
                                       float4* __restrict__ dst, int l) {
    float4 tmp[N4 / 64];
#pragma unroll
    for (int c = 0; c < N4 / 64; ++c) tmp[c] = src[c * 64 + l];
#pragma unroll
    for (int c = 0; c < N4 / 64; ++c) dst[c * 64 + l] = tmp[c];
}

__global__ __launch_bounds__(BLOCK, 2) void nsf_kernel(
    const float* __restrict__ x,
    const float* __restrict__ W_in,  const float* __restrict__ b_in,
    const float* __restrict__ b_blk, const float* __restrict__ b_out,
    const float* __restrict__ wt,    // transposed weights in d_ws
    float* __restrict__ out, int n)
{
    __shared__ float slab [64 * BLOCK];   // 16 KB  [k][tid] per-lane activations
    __shared__ float wtile[64 * 64];      // 16 KB  current layer tile [k][o]

    const int tid = threadIdx.x;
    const int idx = blockIdx.x * BLOCK + tid;
    if (idx >= n) return;

    float4* wtile4 = (float4*)wtile;

    float z0 = x[3 * idx + 0];
    float z1 = x[3 * idx + 1];
    float z2 = x[3 * idx + 2];
    float lad_total = 0.0f;

    float h[HID_];

#pragma unroll 1
    for (int i = 0; i < NT_; ++i) {
        const float ident = z2;
        const float tr0   = z1;
        const float tr1   = z0;

        const float* Wi = W_in + i * HID_;   // uniform, once per transform
        const float* bi = b_in + i * HID_;
#pragma unroll
        for (int o = 0; o < HID_; ++o) h[o] = fmaf(ident, Wi[o], bi[o]);

#pragma unroll 1
        for (int j = 0; j < 2; ++j) {
            const float* bA = b_blk + (i * 4 + 2 * j) * HID_;
            const float* bB = bA + HID_;
            const float4* WT_A4 = (const float4*)(wt + (size_t)(i * 4 + 2 * j) * 4096);
            const float4* WT_B4 = WT_A4 + 1024;

            // ---- dense A: t1 = bA + sum_k relu(h_k) * WA^T[k][:] ----
#pragma unroll
            for (int k = 0; k < HID_; ++k) slab[k * BLOCK + tid] = h[k];
            stage_<1024>(WT_A4, wtile4, tid);

            float t1[HID_];
#pragma unroll
            for (int o = 0; o < HID_; ++o) t1[o] = bA[o];
#pragma unroll 2
            for (int k = 0; k < HID_; ++k) {
                const float rk = fmaxf(slab[k * BLOCK + tid], 0.0f);
                const float4* wr = (const float4*)(wtile + k * 64);  // broadcast
                float4 w[16];
#pragma unroll
                for (int c = 0; c < 16; ++c) w[c] = wr[c];
#pragma unroll
                for (int c = 0; c < 16; ++c) {
                    t1[4 * c + 0] = fmaf(rk, w[c].x, t1[4 * c + 0]);
                    t1[4 * c + 1] = fmaf(rk, w[c].y, t1[4 * c + 1]);
                    t1[4 * c + 2] = fmaf(rk, w[c].z, t1[4 * c + 2]);
                    t1[4 * c + 3] = fmaf(rk, w[c].w, t1[4 * c + 3]);
                }
            }

            // ---- dense B + residual: h += bB + sum_k relu(t1_k) * WB^T ----
#pragma unroll
            for (int k = 0; k < HID_; ++k) slab[k * BLOCK + tid] = fmaxf(t1[k], 0.0f);
            stage_<1024>(WT_B4, wtile4, tid);

#pragma unroll
            for (int o = 0; o < HID_; ++o) h[o] += bB[o];
#pragma unroll 2
            for (int k = 0; k < HID_; ++k) {
                const float rk = slab[k * BLOCK + tid];
                const float4* wr = (const float4*)(wtile + k * 64);
                float4 w[16];
#pragma unroll
                for (int c = 0; c < 16; ++c) w[c] = wr[c];
#pragma unroll
                for (int c = 0; c < 16; ++c) {
                    h[4 * c + 0] = fmaf(rk, w[c].x, h[4 * c + 0]);
                    h[4 * c + 1] = fmaf(rk, w[c].y, h[4 * c + 1]);
                    h[4 * c + 2] = fmaf(rk, w[c].z, h[4 * c + 2]);
                    h[4 * c + 3] = fmaf(rk, w[c].w, h[4 * c + 3]);
                }
            }
        }

        // ---- output head: two 37-wide halves from padded 40-col tiles ----
#pragma unroll
        for (int k = 0; k < HID_; ++k) slab[k * BLOCK + tid] = h[k];

        const float* bo = b_out + i * OD_;
        float y_tr[2], l_tr[2];
        const float trv[2] = { tr0, tr1 };

#pragma unroll 1
        for (int half = 0; half < 2; ++half) {
            const float4* WT_O4 =
                (const float4*)(wt + WT_BLK_ELEMS + (size_t)(i * 2 + half) * 2560);
            stage_<640>(WT_O4, wtile4, tid);

            float p[37];
#pragma unroll
            for (int o = 0; o < 37; ++o) p[o] = bo[half * 37 + o];

#pragma unroll 2
            for (int k = 0; k < HID_; ++k) {
                const float hk = slab[k * BLOCK + tid];
                const float4* wr = (const float4*)(wtile + k * 40);  // broadcast
                float4 w[10];
#pragma unroll
                for (int c = 0; c < 10; ++c) w[c] = wr[c];
#pragma unroll
                for (int c = 0; c < 9; ++c) {
                    p[4 * c + 0] = fmaf(hk, w[c].x, p[4 * c + 0]);
                    p[4 * c + 1] = fmaf(hk, w[c].y, p[4 * c + 1]);
                    p[4 * c + 2] = fmaf(hk, w[c].z, p[4 * c + 2]);
                    p[4 * c + 3] = fmaf(hk, w[c].w, p[4 * c + 3]);
                }
                p[36] = fmaf(hk, w[9].x, p[36]);
            }

            rq_spline_reg(p, trv[half], y_tr[half], l_tr[half]);
        }

        lad_total += l_tr[0] + l_tr[1];

        z0 = ident;
        z1 = y_tr[0];
        z2 = y_tr[1];
    }

    out[idx] = -0.5f * (z0 * z0 + z1 * z1 + z2 * z2) + LOGZ_ + lad_total;
}

}  // namespace

extern "C" void kernel_launch(void* const* d_in, const int* in_sizes, int n_in,
                              void* d_out, int out_size, void* d_ws, size_t ws_size,
                              hipStream_t stream) {
    const float* x     = (const float*)d_in[0];
    const float* W_in  = (const float*)d_in[1];
    const float* b_in  = (const float*)d_in[2];
    const float* W_blk = (const float*)d_in[3];
    const float* b_blk = (const float*)d_in[4];
    const float* W_out = (const float*)d_in[5];
    const float* b_out = (const float*)d_in[6];
    float* out = (float*)d_out;
    float* wt  = (float*)d_ws;   // 688 KB needed

    const int tot = WT_BLK_ELEMS + WT_OUT_ELEMS;           // 172032
    transpose_k<<<(tot + 255) / 256, 256, 0, stream>>>(W_blk, W_out, wt);

    const int n = in_sizes[0] / 3;
    const int grid = (n + BLOCK - 1) / BLOCK;
    nsf_kernel<<<grid, BLOCK, 0, stream>>>(x, W_in, b_in, b_blk, b_out,
                                           wt, out, n);
}

// Round 6
// 6994.653 us; speedup vs baseline: 9.9291x; 1.2288x over previous
//
#include <hip/hip_runtime.h>
#include <math.h>

namespace {

constexpr int   NT_   = 8;
constexpr int   NB_   = 12;
constexpr float TB_   = 5.0f;
constexpr float MINW_ = 0.001f;
constexpr float MINH_ = 0.001f;
constexpr float MIND_ = 0.001f;
constexpr float LOGZ_ = -2.7568155996140185f;  // -0.5*3*log(2*pi)

constexpr int AP_ = 68;   // A-slab pitch (floats): 16B-aligned rows, 2-way banks
constexpr int PP_ = 75;   // param-slab pitch: odd -> 2-way banks on per-lane rows

// d_ws layout (floats):
//   WT_blk[32][64][64]   k-major dense tiles            (131072)
//   WT_out[8][64][80]    k-major head tiles, 80-padded  (40960)
constexpr int WT_BLK_ELEMS = 32 * 64 * 64;
constexpr int WT_OUT_ELEMS = 8 * 64 * 80;

__device__ __forceinline__ float softplus_(float v) {
    return fmaxf(v, 0.0f) + log1pf(__expf(-fabsf(v)));
}

// Rational-quadratic spline, params in registers (verified rounds 4-5).
// p[0..11]=uw, p[12..23]=uh, p[24..36]=ud.
__device__ __forceinline__ void rq_spline_reg(const float (&p)[37], float xr,
                                              float& y_out, float& lad_out) {
    float mw = -1e30f, mh = -1e30f;
#pragma unroll
    for (int q = 0; q < NB_; ++q) { mw = fmaxf(mw, p[q]); mh = fmaxf(mh, p[NB_ + q]); }

    float ew[NB_], eh[NB_];
    float sw = 0.0f, sh = 0.0f;
#pragma unroll
    for (int q = 0; q < NB_; ++q) { ew[q] = __expf(p[q] - mw);        sw += ew[q]; }
#pragma unroll
    for (int q = 0; q < NB_; ++q) { eh[q] = __expf(p[NB_ + q] - mh);  sh += eh[q]; }

    const float iw = (1.0f - MINW_ * (float)NB_) / sw;
    const float ih = (1.0f - MINH_ * (float)NB_) / sh;

    float cw[NB_ + 1], ch[NB_ + 1];
    cw[0] = -TB_; ch[0] = -TB_;
    float rw = 0.0f, rh = 0.0f;
#pragma unroll
    for (int q = 0; q < NB_; ++q) {
        rw += MINW_ + ew[q] * iw;
        rh += MINH_ + eh[q] * ih;
        cw[q + 1] = fmaf(2.0f * TB_, rw, -TB_);
        ch[q + 1] = fmaf(2.0f * TB_, rh, -TB_);
    }
    cw[NB_] = TB_;
    ch[NB_] = TB_;

    const float xc = fminf(fmaxf(xr, -TB_), TB_);

    int bi = 0;
#pragma unroll
    for (int q = 1; q <= NB_ - 1; ++q) bi += (xc >= cw[q]) ? 1 : 0;

    float in_cw = cw[0], cwn = cw[1], in_ch = ch[0], chn = ch[1];
    float udm1 = 0.0f, ud0 = p[24];
#pragma unroll
    for (int q = 1; q < NB_; ++q) {
        const bool s = (bi == q);
        in_cw = s ? cw[q]         : in_cw;
        cwn   = s ? cw[q + 1]     : cwn;
        in_ch = s ? ch[q]         : in_ch;
        chn   = s ? ch[q + 1]     : chn;
        udm1  = s ? p[24 + q - 1] : udm1;
        ud0   = s ? p[24 + q]     : ud0;
    }
    const float in_w = cwn - in_cw;
    const float in_h = chn - in_ch;
    const float d_k  = (bi == 0) ? 1.0f : (MIND_ + softplus_(udm1));
    const float d_k1 = MIND_ + softplus_(ud0);

    const float delta = in_h / in_w;
    const float theta = (xc - in_cw) / in_w;
    const float omt   = 1.0f - theta;
    const float t1m   = theta * omt;
    const float num   = in_h * (delta * theta * theta + d_k * t1m);
    const float den   = delta + (d_k + d_k1 - 2.0f * delta) * t1m;
    const float y     = in_ch + num / den;
    const float dnum  = delta * delta * (d_k1 * theta * theta + 2.0f * delta * t1m + d_k * omt * omt);
    const float lad   = __logf(dnum) - 2.0f * __logf(den);

    const bool inside = (xr >= -TB_) && (xr <= TB_);
    y_out   = inside ? y   : xr;
    lad_out = inside ? lad : 0.0f;
}

// Pre-pass: k-major transposes into d_ws.
__global__ __launch_bounds__(256) void transpose_k(const float* __restrict__ Wb,
                                                   const float* __restrict__ Wo,
                                                   float* __restrict__ wt) {
    const int t = blockIdx.x * 256 + threadIdx.x;
    if (t < WT_BLK_ELEMS) {
        const int l = t >> 12, k = (t >> 6) & 63, o = t & 63;
        wt[t] = Wb[l * 4096 + o * 64 + k];                  // WT[l][k][o]
    } else if (t < WT_BLK_ELEMS + WT_OUT_ELEMS) {
        const int t2 = t - WT_BLK_ELEMS;
        const int i  = t2 / 5120;
        const int r  = t2 - i * 5120;
        const int k  = r / 80;
        const int c  = r - k * 80;
        wt[t] = (c < 74) ? Wo[(i * 74 + c) * 64 + k] : 0.0f;  // WTo[i][k][c]
    }
}

__global__ __launch_bounds__(64, 1) void nsf_kernel(
    const float* __restrict__ x,
    const float* __restrict__ W_in,  const float* __restrict__ b_in,
    const float* __restrict__ b_blk, const float* __restrict__ b_out,
    const float* __restrict__ wt,
    float* __restrict__ out, int n)
{
    __shared__ __align__(16) float As[64 * AP_];   // activations, transposed [k][p]
    __shared__ __align__(16) float Ws[64 * 80];    // weight tile / param slab
    __shared__ __align__(16) float Id[64];         // ident broadcast

    const int l  = threadIdx.x;
    const int pr = l >> 3;      // point-tile 0..7 (points pr*8..pr*8+7)
    const int oc = l & 7;       // output-tile 0..7
    const int gidx = blockIdx.x * 64 + l;
    int idx = gidx < n ? gidx : (n - 1);

    const float4* wt4 = (const float4*)wt;
    float4* Ws4 = (float4*)Ws;

    float z0 = x[3 * idx + 0];
    float z1 = x[3 * idx + 1];
    float z2 = x[3 * idx + 2];
    float lad_total = 0.0f;

#pragma unroll 1
    for (int i = 0; i < NT_; ++i) {
        const float ident = z2;
        const float tr0   = z1;
        const float tr1   = z0;

        Id[l] = ident;

        // stage first dense tile (j=0, layer A) into regs (covers h-init)
        float4 wtmp[16];
        {
            const float4* src = wt4 + (size_t)(i * 4) * 1024;
#pragma unroll
            for (int c = 0; c < 16; ++c) wtmp[c] = src[c * 64 + l];
        }

        // ---- h-init: h[pi][oi] = ident[pr*8+pi]*W_in[oc*8+oi] + b_in ----
        float h[8][8];
        {
            const float4 id0 = *(const float4*)&Id[pr * 8];
            const float4 id1 = *(const float4*)&Id[pr * 8 + 4];
            const float idp[8] = {id0.x, id0.y, id0.z, id0.w,
                                  id1.x, id1.y, id1.z, id1.w};
            const float4 wi0 = *(const float4*)(W_in + i * 64 + oc * 8);
            const float4 wi1 = *(const float4*)(W_in + i * 64 + oc * 8 + 4);
            const float4 bi0 = *(const float4*)(b_in + i * 64 + oc * 8);
            const float4 bi1 = *(const float4*)(b_in + i * 64 + oc * 8 + 4);
            const float wic[8] = {wi0.x, wi0.y, wi0.z, wi0.w,
                                  wi1.x, wi1.y, wi1.z, wi1.w};
            const float bic[8] = {bi0.x, bi0.y, bi0.z, bi0.w,
                                  bi1.x, bi1.y, bi1.z, bi1.w};
#pragma unroll
            for (int pi = 0; pi < 8; ++pi)
#pragma unroll
                for (int oi = 0; oi < 8; ++oi)
                    h[pi][oi] = fmaf(idp[pi], wic[oi], bic[oi]);
        }

#pragma unroll 1
        for (int j = 0; j < 2; ++j) {
            // A-slab := relu(h), transposed: A[oc*8+oi][pr*8+pi]
#pragma unroll
            for (int oi = 0; oi < 8; ++oi) {
                float4 u0 = {fmaxf(h[0][oi], 0.f), fmaxf(h[1][oi], 0.f),
                             fmaxf(h[2][oi], 0.f), fmaxf(h[3][oi], 0.f)};
                float4 u1 = {fmaxf(h[4][oi], 0.f), fmaxf(h[5][oi], 0.f),
                             fmaxf(h[6][oi], 0.f), fmaxf(h[7][oi], 0.f)};
                *(float4*)&As[(oc * 8 + oi) * AP_ + pr * 8]     = u0;
                *(float4*)&As[(oc * 8 + oi) * AP_ + pr * 8 + 4] = u1;
            }
            // Ws := staged dense-A tile
#pragma unroll
            for (int c = 0; c < 16; ++c) Ws4[c * 64 + l] = wtmp[c];

            // ---- dense A: acc = A^T W ----
            float acc[8][8] = {};
#pragma unroll 2
            for (int k = 0; k < 64; ++k) {
                const float4 a0 = *(const float4*)&As[k * AP_ + pr * 8];
                const float4 a1 = *(const float4*)&As[k * AP_ + pr * 8 + 4];
                const float4 w0 = *(const float4*)&Ws[k * 64 + oc * 8];
                const float4 w1 = *(const float4*)&Ws[k * 64 + oc * 8 + 4];
                const float av[8] = {a0.x, a0.y, a0.z, a0.w, a1.x, a1.y, a1.z, a1.w};
                const float wv[8] = {w0.x, w0.y, w0.z, w0.w, w1.x, w1.y, w1.z, w1.w};
#pragma unroll
                for (int pi = 0; pi < 8; ++pi)
#pragma unroll
                    for (int oi = 0; oi < 8; ++oi)
                        acc[pi][oi] = fmaf(av[pi], wv[oi], acc[pi][oi]);
            }

            // stage dense-B tile (covers epilogue below)
            {
                const float4* src = wt4 + (size_t)(i * 4 + 2 * j + 1) * 1024;
#pragma unroll
                for (int c = 0; c < 16; ++c) wtmp[c] = src[c * 64 + l];
            }

            // A-slab := relu(acc + bA), transposed
            const float4 ba0 = *(const float4*)(b_blk + (i * 4 + 2 * j) * 64 + oc * 8);
            const float4 ba1 = *(const float4*)(b_blk + (i * 4 + 2 * j) * 64 + oc * 8 + 4);
            const float bac[8] = {ba0.x, ba0.y, ba0.z, ba0.w,
                                  ba1.x, ba1.y, ba1.z, ba1.w};
#pragma unroll
            for (int oi = 0; oi < 8; ++oi) {
                float4 u0 = {fmaxf(acc[0][oi] + bac[oi], 0.f), fmaxf(acc[1][oi] + bac[oi], 0.f),
                             fmaxf(acc[2][oi] + bac[oi], 0.f), fmaxf(acc[3][oi] + bac[oi], 0.f)};
                float4 u1 = {fmaxf(acc[4][oi] + bac[oi], 0.f), fmaxf(acc[5][oi] + bac[oi], 0.f),
                             fmaxf(acc[6][oi] + bac[oi], 0.f), fmaxf(acc[7][oi] + bac[oi], 0.f)};
                *(float4*)&As[(oc * 8 + oi) * AP_ + pr * 8]     = u0;
                *(float4*)&As[(oc * 8 + oi) * AP_ + pr * 8 + 4] = u1;
            }
#pragma unroll
            for (int c = 0; c < 16; ++c) Ws4[c * 64 + l] = wtmp[c];

            // ---- dense B ----
            float acc2[8][8] = {};
#pragma unroll 2
            for (int k = 0; k < 64; ++k) {
                const float4 a0 = *(const float4*)&As[k * AP_ + pr * 8];
                const float4 a1 = *(const float4*)&As[k * AP_ + pr * 8 + 4];
                const float4 w0 = *(const float4*)&Ws[k * 64 + oc * 8];
                const float4 w1 = *(const float4*)&Ws[k * 64 + oc * 8 + 4];
                const float av[8] = {a0.x, a0.y, a0.z, a0.w, a1.x, a1.y, a1.z, a1.w};
                const float wv[8] = {w0.x, w0.y, w0.z, w0.w, w1.x, w1.y, w1.z, w1.w};
#pragma unroll
                for (int pi = 0; pi < 8; ++pi)
#pragma unroll
                    for (int oi = 0; oi < 8; ++oi)
                        acc2[pi][oi] = fmaf(av[pi], wv[oi], acc2[pi][oi]);
            }

            // residual: h += acc2 + bB
            const float4 bb0 = *(const float4*)(b_blk + (i * 4 + 2 * j + 1) * 64 + oc * 8);
            const float4 bb1 = *(const float4*)(b_blk + (i * 4 + 2 * j + 1) * 64 + oc * 8 + 4);
            const float bbc[8] = {bb0.x, bb0.y, bb0.z, bb0.w,
                                  bb1.x, bb1.y, bb1.z, bb1.w};
#pragma unroll
            for (int pi = 0; pi < 8; ++pi)
#pragma unroll
                for (int oi = 0; oi < 8; ++oi)
                    h[pi][oi] += acc2[pi][oi] + bbc[oi];

            // stage next dense-A tile (j=1) during this epilogue
            if (j == 0) {
                const float4* src = wt4 + (size_t)(i * 4 + 2) * 1024;
#pragma unroll
                for (int c = 0; c < 16; ++c) wtmp[c] = src[c * 64 + l];
            }
        }

        // ---- output head: 80-padded, lane tile 8p x 10o ----
        float4 wh[20];
        {
            const float4* src = wt4 + (WT_BLK_ELEMS / 4) + (size_t)i * 1280;
#pragma unroll
            for (int c = 0; c < 20; ++c) wh[c] = src[c * 64 + l];
        }
        // A-slab := h (NO relu), transposed
#pragma unroll
        for (int oi = 0; oi < 8; ++oi) {
            float4 u0 = {h[0][oi], h[1][oi], h[2][oi], h[3][oi]};
            float4 u1 = {h[4][oi], h[5][oi], h[6][oi], h[7][oi]};
            *(float4*)&As[(oc * 8 + oi) * AP_ + pr * 8]     = u0;
            *(float4*)&As[(oc * 8 + oi) * AP_ + pr * 8 + 4] = u1;
        }
#pragma unroll
        for (int c = 0; c < 20; ++c) Ws4[c * 64 + l] = wh[c];

        float acc3[8][10] = {};
#pragma unroll 2
        for (int k = 0; k < 64; ++k) {
            const float4 a0 = *(const float4*)&As[k * AP_ + pr * 8];
            const float4 a1 = *(const float4*)&As[k * AP_ + pr * 8 + 4];
            const float av[8] = {a0.x, a0.y, a0.z, a0.w, a1.x, a1.y, a1.z, a1.w};
            const float2 q0 = *(const float2*)&Ws[k * 80 + oc * 10 + 0];
            const float2 q1 = *(const float2*)&Ws[k * 80 + oc * 10 + 2];
            const float2 q2 = *(const float2*)&Ws[k * 80 + oc * 10 + 4];
            const float2 q3 = *(const float2*)&Ws[k * 80 + oc * 10 + 6];
            const float2 q4 = *(const float2*)&Ws[k * 80 + oc * 10 + 8];
            const float wv[10] = {q0.x, q0.y, q1.x, q1.y, q2.x,
                                  q2.y, q3.x, q3.y, q4.x, q4.y};
#pragma unroll
            for (int pi = 0; pi < 8; ++pi)
#pragma unroll
                for (int m = 0; m < 10; ++m)
                    acc3[pi][m] = fmaf(av[pi], wv[m], acc3[pi][m]);
        }

        // params -> P-slab (reusing Ws), row = point, pitch PP_, cols < 74
#pragma unroll
        for (int pi = 0; pi < 8; ++pi) {
#pragma unroll
            for (int m = 0; m < 10; ++m) {
                if (oc < 7 || m < 4)
                    Ws[(pr * 8 + pi) * PP_ + oc * 10 + m] = acc3[pi][m];
            }
        }

        // ---- spline (lane = point l), bias added from uniform b_out ----
        const float* bo = b_out + i * 74;
        float p0[37], p1[37];
#pragma unroll
        for (int q = 0; q < 37; ++q) p0[q] = Ws[l * PP_ + q] + bo[q];
#pragma unroll
        for (int q = 0; q < 37; ++q) p1[q] = Ws[l * PP_ + 37 + q] + bo[37 + q];

        float y0, l0v, y1, l1v;
        rq_spline_reg(p0, tr0, y0, l0v);
        rq_spline_reg(p1, tr1, y1, l1v);
        lad_total += l0v + l1v;

        z0 = ident;
        z1 = y0;
        z2 = y1;
    }

    if (gidx < n)
        out[gidx] = -0.5f * (z0 * z0 + z1 * z1 + z2 * z2) + LOGZ_ + lad_total;
}

}  // namespace

extern "C" void kernel_launch(void* const* d_in, const int* in_sizes, int n_in,
                              void* d_out, int out_size, void* d_ws, size_t ws_size,
                              hipStream_t stream) {
    const float* x     = (const float*)d_in[0];
    const float* W_in  = (const float*)d_in[1];
    const float* b_in  = (const float*)d_in[2];
    const float* W_blk = (const float*)d_in[3];
    const float* b_blk = (const float*)d_in[4];
    const float* W_out = (const float*)d_in[5];
    const float* b_out = (const float*)d_in[6];
    float* out = (float*)d_out;
    float* wt  = (float*)d_ws;   // 688 KB needed

    const int tot = WT_BLK_ELEMS + WT_OUT_ELEMS;   // 172032
    transpose_k<<<(tot + 255) / 256, 256, 0, stream>>>(W_blk, W_out, wt);

    const int n = in_sizes[0] / 3;
    const int grid = (n + 63) / 64;
    nsf_kernel<<<grid, 64, 0, stream>>>(x, W_in, b_in, b_blk, b_out,
                                        wt, out, n);
}

// Round 7
// 5929.872 us; speedup vs baseline: 11.7119x; 1.1796x over previous
//
#include <hip/hip_runtime.h>
#include <math.h>

namespace {

constexpr int   NT_   = 8;
constexpr int   NB_   = 12;
constexpr float TB_   = 5.0f;
constexpr float MINW_ = 0.001f;
constexpr float MINH_ = 0.001f;
constexpr float MIND_ = 0.001f;
constexpr float LOGZ_ = -2.7568155996140185f;  // -0.5*3*log(2*pi)

constexpr int AP_  = 68;        // A-slab row pitch (floats), rows 16B-aligned
constexpr int ASZ_ = 64 * AP_;  // per-wave A-slab floats (4352)
constexpr int PPP_ = 41;        // param-slab pitch (odd -> 2-way banks, free)

// d_ws layout (floats):
//   WT_blk[32][64][64]      k-major dense tiles              (131072)
//   WT_out[8][2][64][40]    k-major head halves, 40-padded   (40960)
constexpr int WT_BLK_ELEMS = 32 * 4096;
constexpr int WT_OUT_ELEMS = 16 * 2560;

__device__ __forceinline__ float softplus_(float v) {
    return fmaxf(v, 0.0f) + log1pf(__expf(-fabsf(v)));
}

// Rational-quadratic spline, params in registers (verified rounds 4-6).
__device__ __forceinline__ void rq_spline_reg(const float (&p)[37], float xr,
                                              float& y_out, float& lad_out) {
    float mw = -1e30f, mh = -1e30f;
#pragma unroll
    for (int q = 0; q < NB_; ++q) { mw = fmaxf(mw, p[q]); mh = fmaxf(mh, p[NB_ + q]); }

    float ew[NB_], eh[NB_];
    float sw = 0.0f, sh = 0.0f;
#pragma unroll
    for (int q = 0; q < NB_; ++q) { ew[q] = __expf(p[q] - mw);        sw += ew[q]; }
#pragma unroll
    for (int q = 0; q < NB_; ++q) { eh[q] = __expf(p[NB_ + q] - mh);  sh += eh[q]; }

    const float iw = (1.0f - MINW_ * (float)NB_) / sw;
    const float ih = (1.0f - MINH_ * (float)NB_) / sh;

    float cw[NB_ + 1], ch[NB_ + 1];
    cw[0] = -TB_; ch[0] = -TB_;
    float rw = 0.0f, rh = 0.0f;
#pragma unroll
    for (int q = 0; q < NB_; ++q) {
        rw += MINW_ + ew[q] * iw;
        rh += MINH_ + eh[q] * ih;
        cw[q + 1] = fmaf(2.0f * TB_, rw, -TB_);
        ch[q + 1] = fmaf(2.0f * TB_, rh, -TB_);
    }
    cw[NB_] = TB_;
    ch[NB_] = TB_;

    const float xc = fminf(fmaxf(xr, -TB_), TB_);

    int bi = 0;
#pragma unroll
    for (int q = 1; q <= NB_ - 1; ++q) bi += (xc >= cw[q]) ? 1 : 0;

    float in_cw = cw[0], cwn = cw[1], in_ch = ch[0], chn = ch[1];
    float udm1 = 0.0f, ud0 = p[24];
#pragma unroll
    for (int q = 1; q < NB_; ++q) {
        const bool s = (bi == q);
        in_cw = s ? cw[q]         : in_cw;
        cwn   = s ? cw[q + 1]     : cwn;
        in_ch = s ? ch[q]         : in_ch;
        chn   = s ? ch[q + 1]     : chn;
        udm1  = s ? p[24 + q - 1] : udm1;
        ud0   = s ? p[24 + q]     : ud0;
    }
    const float in_w = cwn - in_cw;
    const float in_h = chn - in_ch;
    const float d_k  = (bi == 0) ? 1.0f : (MIND_ + softplus_(udm1));
    const float d_k1 = MIND_ + softplus_(ud0);

    const float delta = in_h / in_w;
    const float theta = (xc - in_cw) / in_w;
    const float omt   = 1.0f - theta;
    const float t1m   = theta * omt;
    const float num   = in_h * (delta * theta * theta + d_k * t1m);
    const float den   = delta + (d_k + d_k1 - 2.0f * delta) * t1m;
    const float y     = in_ch + num / den;
    const float dnum  = delta * delta * (d_k1 * theta * theta + 2.0f * delta * t1m + d_k * omt * omt);
    const float lad   = __logf(dnum) - 2.0f * __logf(den);

    const bool inside = (xr >= -TB_) && (xr <= TB_);
    y_out   = inside ? y   : xr;
    lad_out = inside ? lad : 0.0f;
}

__global__ __launch_bounds__(256) void transpose_k(const float* __restrict__ Wb,
                                                   const float* __restrict__ Wo,
                                                   float* __restrict__ wt) {
    const int t = blockIdx.x * 256 + threadIdx.x;
    if (t < WT_BLK_ELEMS) {
        const int l = t >> 12, k = (t >> 6) & 63, o = t & 63;
        wt[t] = Wb[l * 4096 + o * 64 + k];                    // WT[l][k][o]
    } else if (t < WT_BLK_ELEMS + WT_OUT_ELEMS) {
        const int t2 = t - WT_BLK_ELEMS;
        const int ih = t2 / 2560;              // i*2 + half
        const int r  = t2 - ih * 2560;
        const int k  = r / 40;
        const int c  = r - k * 40;
        const int i  = ih >> 1, half = ih & 1;
        wt[t] = (c < 37) ? Wo[(i * 74 + half * 37 + c) * 64 + k] : 0.0f;
    }
}

// Async stage NC 1024B-chunks global -> LDS; the block's two waves split them.
template <int NC>
__device__ __forceinline__ void stage_(const float* __restrict__ g, float* lds,
                                       int wave, int wl) {
#pragma unroll
    for (int c = 0; c < NC / 2; ++c) {
        const int cc = wave * (NC / 2) + c;
        __builtin_amdgcn_global_load_lds(
            (const __attribute__((address_space(1))) void*)(g + cc * 256 + wl * 4),
            (__attribute__((address_space(3))) void*)(lds + cc * 256), 16, 0, 0);
    }
}

// acc[pi][oi] += (relu?)A[p][k] * W[k][o] over k=0..63
template <bool RELU>
__device__ __forceinline__ void dense64_(const float* AsW, const float* Ws,
                                         int pr2, int oc, float (&acc)[8][8]) {
#pragma unroll 2
    for (int k = 0; k < 64; ++k) {
        const int key = (k >> 3) & 7;
        const float4 a0 = *(const float4*)&AsW[k * AP_ + ((pr2    ) ^ key) * 4];
        const float4 a1 = *(const float4*)&AsW[k * AP_ + ((pr2 + 1) ^ key) * 4];
        const float4 w0 = *(const float4*)&Ws[k * 64 + oc * 8];
        const float4 w1 = *(const float4*)&Ws[k * 64 + oc * 8 + 4];
        float av[8] = {a0.x, a0.y, a0.z, a0.w, a1.x, a1.y, a1.z, a1.w};
        const float wv[8] = {w0.x, w0.y, w0.z, w0.w, w1.x, w1.y, w1.z, w1.w};
        if (RELU) {
#pragma unroll
            for (int t = 0; t < 8; ++t) av[t] = fmaxf(av[t], 0.0f);
        }
#pragma unroll
        for (int pi = 0; pi < 8; ++pi)
#pragma unroll
            for (int oi = 0; oi < 8; ++oi)
                acc[pi][oi] = fmaf(av[pi], wv[oi], acc[pi][oi]);
    }
}

// head half: acc[pi][m] += A[p][k] * Wh[k][oc+8m], raw A
__device__ __forceinline__ void head40_(const float* AsW, const float* Ws,
                                        int pr2, int oc, float (&acc)[8][5]) {
#pragma unroll 2
    for (int k = 0; k < 64; ++k) {
        const int key = (k >> 3) & 7;
        const float4 a0 = *(const float4*)&AsW[k * AP_ + ((pr2    ) ^ key) * 4];
        const float4 a1 = *(const float4*)&AsW[k * AP_ + ((pr2 + 1) ^ key) * 4];
        const float av[8] = {a0.x, a0.y, a0.z, a0.w, a1.x, a1.y, a1.z, a1.w};
        float wv[5];
#pragma unroll
        for (int m = 0; m < 5; ++m) wv[m] = Ws[k * 40 + oc + 8 * m];
#pragma unroll
        for (int pi = 0; pi < 8; ++pi)
#pragma unroll
            for (int m = 0; m < 5; ++m)
                acc[pi][m] = fmaf(av[pi], wv[m], acc[pi][m]);
    }
}

// write 8x8 tile (raw) to swizzled A-slab
__device__ __forceinline__ void writeA_(float* AsW, int pr2, int oc,
                                        const float (&v)[8][8]) {
#pragma unroll
    for (int oi = 0; oi < 8; ++oi) {
        float4 u0 = {v[0][oi], v[1][oi], v[2][oi], v[3][oi]};
        float4 u1 = {v[4][oi], v[5][oi], v[6][oi], v[7][oi]};
        *(float4*)&AsW[(oc * 8 + oi) * AP_ + ((pr2    ) ^ oc) * 4] = u0;
        *(float4*)&AsW[(oc * 8 + oi) * AP_ + ((pr2 + 1) ^ oc) * 4] = u1;
    }
}

// acc = t1: read raw h tile, overwrite slab with relu(t1), acc := h + bB[oi]
__device__ __forceinline__ void transition_(float* AsW, int pr2, int oc,
                                            float (&acc)[8][8], const float (&bbc)[8]) {
#pragma unroll
    for (int oi = 0; oi < 8; ++oi) {
        float* q0 = &AsW[(oc * 8 + oi) * AP_ + ((pr2    ) ^ oc) * 4];
        float* q1 = &AsW[(oc * 8 + oi) * AP_ + ((pr2 + 1) ^ oc) * 4];
        const float4 h0 = *(const float4*)q0;
        const float4 h1 = *(const float4*)q1;
        float4 r0 = {fmaxf(acc[0][oi], 0.f), fmaxf(acc[1][oi], 0.f),
                     fmaxf(acc[2][oi], 0.f), fmaxf(acc[3][oi], 0.f)};
        float4 r1 = {fmaxf(acc[4][oi], 0.f), fmaxf(acc[5][oi], 0.f),
                     fmaxf(acc[6][oi], 0.f), fmaxf(acc[7][oi], 0.f)};
        *(float4*)q0 = r0;
        *(float4*)q1 = r1;
        acc[0][oi] = h0.x + bbc[oi]; acc[1][oi] = h0.y + bbc[oi];
        acc[2][oi] = h0.z + bbc[oi]; acc[3][oi] = h0.w + bbc[oi];
        acc[4][oi] = h1.x + bbc[oi]; acc[5][oi] = h1.y + bbc[oi];
        acc[6][oi] = h1.z + bbc[oi]; acc[7][oi] = h1.w + bbc[oi];
    }
}

__device__ __forceinline__ void load8_(const float* p, float (&d)[8]) {
    const float4 a = *(const float4*)p;
    const float4 b = *(const float4*)(p + 4);
    d[0] = a.x; d[1] = a.y; d[2] = a.z; d[3] = a.w;
    d[4] = b.x; d[5] = b.y; d[6] = b.z; d[7] = b.w;
}

__global__ __launch_bounds__(128, 1) void nsf_kernel(
    const float* __restrict__ x,
    const float* __restrict__ W_in,  const float* __restrict__ b_in,
    const float* __restrict__ b_blk, const float* __restrict__ b_out,
    const float* __restrict__ wt,
    float* __restrict__ out, int n)
{
    __shared__ __align__(16) float As2[2 * ASZ_];   // 34816 B, per-wave slabs
    __shared__ __align__(16) float Ws[4096];        // 16384 B, shared tile
    __shared__ float Id[128];

    const int l    = threadIdx.x;
    const int wave = l >> 6;
    const int wl   = l & 63;
    const int pr   = wl >> 3, oc = wl & 7, pr2 = pr * 2;
    float* AsW = As2 + wave * ASZ_;

    const int gidx = blockIdx.x * 128 + l;
    const int idx  = gidx < n ? gidx : (n - 1);

    float z0 = x[3 * idx + 0];
    float z1 = x[3 * idx + 1];
    float z2 = x[3 * idx + 2];
    float lad_total = 0.0f;

    stage_<16>(wt, Ws, wave, wl);   // transform 0, dense tile A0

#pragma unroll 1
    for (int i = 0; i < NT_; ++i) {
        const float ident = z2;
        const float tr0   = z1;
        const float tr1   = z0;

        Id[l] = ident;

        // ---- h-init -> raw h into A-slab ----
        {
            float idp[8], wic[8], bic[8];
            load8_(&Id[wave * 64 + pr * 8], idp);
            load8_(W_in + i * 64 + oc * 8, wic);
            load8_(b_in + i * 64 + oc * 8, bic);
            float hh[8][8];
#pragma unroll
            for (int pi = 0; pi < 8; ++pi)
#pragma unroll
                for (int oi = 0; oi < 8; ++oi)
                    hh[pi][oi] = fmaf(idp[pi], wic[oi], bic[oi]);
            writeA_(AsW, pr2, oc, hh);
        }

        float acc[8][8];

#pragma unroll 1
        for (int j = 0; j < 2; ++j) {
            const int LA = i * 4 + 2 * j;
            float bac[8], bbc[8];
            load8_(b_blk + LA * 64 + oc * 8, bac);
            load8_(b_blk + (LA + 1) * 64 + oc * 8, bbc);

            __syncthreads();                       // dense-A tile ready
#pragma unroll
            for (int pi = 0; pi < 8; ++pi)
#pragma unroll
                for (int oi = 0; oi < 8; ++oi) acc[pi][oi] = bac[oi];
            dense64_<true>(AsW, Ws, pr2, oc, acc); // acc = t1 (relu on A)
            __syncthreads();                       // tile consumed

            stage_<16>(wt + (size_t)(LA + 1) * 4096, Ws, wave, wl);
            transition_(AsW, pr2, oc, acc, bbc);   // slab:=relu(t1), acc:=h+bB
            __syncthreads();                       // dense-B tile ready

            dense64_<false>(AsW, Ws, pr2, oc, acc);// acc = h_new
            __syncthreads();                       // tile consumed

            if (j == 0) {
                stage_<16>(wt + (size_t)(LA + 2) * 4096, Ws, wave, wl);
            } else {
                stage_<10>(wt + WT_BLK_ELEMS + (size_t)(i * 2) * 2560, Ws, wave, wl);
            }
            writeA_(AsW, pr2, oc, acc);            // raw h back to slab
        }

        // ---- output head: two 40-wide halves, raw h operand ----
        float acc30[8][5] = {};
        float acc31[8][5] = {};
        __syncthreads();                           // head half-0 tile ready
        head40_(AsW, Ws, pr2, oc, acc30);
        __syncthreads();
        stage_<10>(wt + WT_BLK_ELEMS + (size_t)(i * 2 + 1) * 2560, Ws, wave, wl);
        __syncthreads();                           // head half-1 tile ready
        head40_(AsW, Ws, pr2, oc, acc31);
        __syncthreads();                           // Ws free for next transform

        if (i < NT_ - 1) stage_<16>(wt + (size_t)((i + 1) * 4) * 4096, Ws, wave, wl);

        // ---- params via per-wave slab (A-slab reused), then splines ----
        const float* bo = b_out + i * 74;
        float y0, l0v, y1, l1v;
        {
#pragma unroll
            for (int pi = 0; pi < 8; ++pi)
#pragma unroll
                for (int m = 0; m < 5; ++m) {
                    const int q = oc + 8 * m;
                    if (q < 37) AsW[(pr * 8 + pi) * PPP_ + q] = acc30[pi][m];
                }
            float p0[37];
#pragma unroll
            for (int q = 0; q < 37; ++q) p0[q] = AsW[wl * PPP_ + q] + bo[q];
            rq_spline_reg(p0, tr0, y0, l0v);
        }
        {
#pragma unroll
            for (int pi = 0; pi < 8; ++pi)
#pragma unroll
                for (int m = 0; m < 5; ++m) {
                    const int q = oc + 8 * m;
                    if (q < 37) AsW[(pr * 8 + pi) * PPP_ + q] = acc31[pi][m];
                }
            float p1[37];
#pragma unroll
            for (int q = 0; q < 37; ++q) p1[q] = AsW[wl * PPP_ + q] + bo[37 + q];
            rq_spline_reg(p1, tr1, y1, l1v);
        }

        lad_total += l0v + l1v;
        z0 = ident;
        z1 = y0;
        z2 = y1;
    }

    if (gidx < n)
        out[gidx] = -0.5f * (z0 * z0 + z1 * z1 + z2 * z2) + LOGZ_ + lad_total;
}

}  // namespace

extern "C" void kernel_launch(void* const* d_in, const int* in_sizes, int n_in,
                              void* d_out, int out_size, void* d_ws, size_t ws_size,
                              hipStream_t stream) {
    const float* x     = (const float*)d_in[0];
    const float* W_in  = (const float*)d_in[1];
    const float* b_in  = (const float*)d_in[2];
    const float* W_blk = (const float*)d_in[3];
    const float* b_blk = (const float*)d_in[4];
    const float* W_out = (const float*)d_in[5];
    const float* b_out = (const float*)d_in[6];
    float* out = (float*)d_out;
    float* wt  = (float*)d_ws;   // 688 KB needed

    const int tot = WT_BLK_ELEMS + WT_OUT_ELEMS;   // 172032
    transpose_k<<<(tot + 255) / 256, 256, 0, stream>>>(W_blk, W_out, wt);

    const int n = in_sizes[0] / 3;
    const int grid = (n + 127) / 128;
    nsf_kernel<<<grid, 128, 0, stream>>>(x, W_in, b_in, b_blk, b_out,
                                         wt, out, n);
}

// Round 8
// 4682.290 us; speedup vs baseline: 14.8326x; 1.2664x over previous
//
#include <hip/hip_runtime.h>
#include <math.h>

namespace {

constexpr int   NT_   = 8;
constexpr int   NB_   = 12;
constexpr float TB_   = 5.0f;
constexpr float MINW_ = 0.001f;
constexpr float MINH_ = 0.001f;
constexpr float MIND_ = 0.001f;
constexpr float LOGZ_ = -2.7568155996140185f;  // -0.5*3*log(2*pi)

constexpr int AP_  = 64;        // A-slab row pitch (floats); XOR swizzle balances banks
constexpr int ASZ_ = 64 * AP_;  // per-wave A-slab floats (4096)
constexpr int PPP_ = 41;        // param-slab pitch (odd -> 2-way banks, free)
constexpr int WAVES_ = 4;       // waves per block

// d_ws layout (floats):
//   WT_blk[32][64][64]      k-major dense tiles              (131072)
//   WT_out[8][2][64][40]    k-major head halves, 40-padded   (40960)
constexpr int WT_BLK_ELEMS = 32 * 4096;
constexpr int WT_OUT_ELEMS = 16 * 2560;

__device__ __forceinline__ float softplus_(float v) {
    return fmaxf(v, 0.0f) + log1pf(__expf(-fabsf(v)));
}

// Rational-quadratic spline, params in registers (verified rounds 4-7).
__device__ __forceinline__ void rq_spline_reg(const float (&p)[37], float xr,
                                              float& y_out, float& lad_out) {
    float mw = -1e30f, mh = -1e30f;
#pragma unroll
    for (int q = 0; q < NB_; ++q) { mw = fmaxf(mw, p[q]); mh = fmaxf(mh, p[NB_ + q]); }

    float ew[NB_], eh[NB_];
    float sw = 0.0f, sh = 0.0f;
#pragma unroll
    for (int q = 0; q < NB_; ++q) { ew[q] = __expf(p[q] - mw);        sw += ew[q]; }
#pragma unroll
    for (int q = 0; q < NB_; ++q) { eh[q] = __expf(p[NB_ + q] - mh);  sh += eh[q]; }

    const float iw = (1.0f - MINW_ * (float)NB_) / sw;
    const float ih = (1.0f - MINH_ * (float)NB_) / sh;

    float cw[NB_ + 1], ch[NB_ + 1];
    cw[0] = -TB_; ch[0] = -TB_;
    float rw = 0.0f, rh = 0.0f;
#pragma unroll
    for (int q = 0; q < NB_; ++q) {
        rw += MINW_ + ew[q] * iw;
        rh += MINH_ + eh[q] * ih;
        cw[q + 1] = fmaf(2.0f * TB_, rw, -TB_);
        ch[q + 1] = fmaf(2.0f * TB_, rh, -TB_);
    }
    cw[NB_] = TB_;
    ch[NB_] = TB_;

    const float xc = fminf(fmaxf(xr, -TB_), TB_);

    int bi = 0;
#pragma unroll
    for (int q = 1; q <= NB_ - 1; ++q) bi += (xc >= cw[q]) ? 1 : 0;

    float in_cw = cw[0], cwn = cw[1], in_ch = ch[0], chn = ch[1];
    float udm1 = 0.0f, ud0 = p[24];
#pragma unroll
    for (int q = 1; q < NB_; ++q) {
        const bool s = (bi == q);
        in_cw = s ? cw[q]         : in_cw;
        cwn   = s ? cw[q + 1]     : cwn;
        in_ch = s ? ch[q]         : in_ch;
        chn   = s ? ch[q + 1]     : chn;
        udm1  = s ? p[24 + q - 1] : udm1;
        ud0   = s ? p[24 + q]     : ud0;
    }
    const float in_w = cwn - in_cw;
    const float in_h = chn - in_ch;
    const float d_k  = (bi == 0) ? 1.0f : (MIND_ + softplus_(udm1));
    const float d_k1 = MIND_ + softplus_(ud0);

    const float delta = in_h / in_w;
    const float theta = (xc - in_cw) / in_w;
    const float omt   = 1.0f - theta;
    const float t1m   = theta * omt;
    const float num   = in_h * (delta * theta * theta + d_k * t1m);
    const float den   = delta + (d_k + d_k1 - 2.0f * delta) * t1m;
    const float y     = in_ch + num / den;
    const float dnum  = delta * delta * (d_k1 * theta * theta + 2.0f * delta * t1m + d_k * omt * omt);
    const float lad   = __logf(dnum) - 2.0f * __logf(den);

    const bool inside = (xr >= -TB_) && (xr <= TB_);
    y_out   = inside ? y   : xr;
    lad_out = inside ? lad : 0.0f;
}

__global__ __launch_bounds__(256) void transpose_k(const float* __restrict__ Wb,
                                                   const float* __restrict__ Wo,
                                                   float* __restrict__ wt) {
    const int t = blockIdx.x * 256 + threadIdx.x;
    if (t < WT_BLK_ELEMS) {
        const int l = t >> 12, k = (t >> 6) & 63, o = t & 63;
        wt[t] = Wb[l * 4096 + o * 64 + k];                    // WT[l][k][o]
    } else if (t < WT_BLK_ELEMS + WT_OUT_ELEMS) {
        const int t2 = t - WT_BLK_ELEMS;
        const int ih = t2 / 2560;              // i*2 + half
        const int r  = t2 - ih * 2560;
        const int k  = r / 40;
        const int c  = r - k * 40;
        const int i  = ih >> 1, half = ih & 1;
        wt[t] = (c < 37) ? Wo[(i * 74 + half * 37 + c) * 64 + k] : 0.0f;
    }
}

// Async stage NC 1024B-chunks global -> LDS; the block's WAVES_ waves split them.
template <int NC>
__device__ __forceinline__ void stage_(const float* __restrict__ g, float* lds,
                                       int wave, int wl) {
#pragma unroll
    for (int c = 0; c < (NC + WAVES_ - 1) / WAVES_; ++c) {
        const int cc = wave + WAVES_ * c;
        if (cc < NC) {
            __builtin_amdgcn_global_load_lds(
                (const __attribute__((address_space(1))) void*)(g + cc * 256 + wl * 4),
                (__attribute__((address_space(3))) void*)(lds + cc * 256), 16, 0, 0);
        }
    }
}

// acc[pi][oi] += (relu?)A[p][k] * W[k][o] over k=0..63
template <bool RELU>
__device__ __forceinline__ void dense64_(const float* AsW, const float* Ws,
                                         int pr2, int oc, float (&acc)[8][8]) {
#pragma unroll 2
    for (int k = 0; k < 64; ++k) {
        const int key = (k >> 3) & 7;
        const float4 a0 = *(const float4*)&AsW[k * AP_ + ((pr2    ) ^ key) * 4];
        const float4 a1 = *(const float4*)&AsW[k * AP_ + ((pr2 + 1) ^ key) * 4];
        const float4 w0 = *(const float4*)&Ws[k * 64 + oc * 8];
        const float4 w1 = *(const float4*)&Ws[k * 64 + oc * 8 + 4];
        float av[8] = {a0.x, a0.y, a0.z, a0.w, a1.x, a1.y, a1.z, a1.w};
        const float wv[8] = {w0.x, w0.y, w0.z, w0.w, w1.x, w1.y, w1.z, w1.w};
        if (RELU) {
#pragma unroll
            for (int t = 0; t < 8; ++t) av[t] = fmaxf(av[t], 0.0f);
        }
#pragma unroll
        for (int pi = 0; pi < 8; ++pi)
#pragma unroll
            for (int oi = 0; oi < 8; ++oi)
                acc[pi][oi] = fmaf(av[pi], wv[oi], acc[pi][oi]);
    }
}

// head half: acc[pi][m] += A[p][k] * Wh[k][oc+8m], raw A
__device__ __forceinline__ void head40_(const float* AsW, const float* Ws,
                                        int pr2, int oc, float (&acc)[8][5]) {
#pragma unroll 2
    for (int k = 0; k < 64; ++k) {
        const int key = (k >> 3) & 7;
        const float4 a0 = *(const float4*)&AsW[k * AP_ + ((pr2    ) ^ key) * 4];
        const float4 a1 = *(const float4*)&AsW[k * AP_ + ((pr2 + 1) ^ key) * 4];
        const float av[8] = {a0.x, a0.y, a0.z, a0.w, a1.x, a1.y, a1.z, a1.w};
        float wv[5];
#pragma unroll
        for (int m = 0; m < 5; ++m) wv[m] = Ws[k * 40 + oc + 8 * m];
#pragma unroll
        for (int pi = 0; pi < 8; ++pi)
#pragma unroll
            for (int m = 0; m < 5; ++m)
                acc[pi][m] = fmaf(av[pi], wv[m], acc[pi][m]);
    }
}

// write 8x8 tile (raw) to swizzled A-slab
__device__ __forceinline__ void writeA_(float* AsW, int pr2, int oc,
                                        const float (&v)[8][8]) {
#pragma unroll
    for (int oi = 0; oi < 8; ++oi) {
        float4 u0 = {v[0][oi], v[1][oi], v[2][oi], v[3][oi]};
        float4 u1 = {v[4][oi], v[5][oi], v[6][oi], v[7][oi]};
        *(float4*)&AsW[(oc * 8 + oi) * AP_ + ((pr2    ) ^ oc) * 4] = u0;
        *(float4*)&AsW[(oc * 8 + oi) * AP_ + ((pr2 + 1) ^ oc) * 4] = u1;
    }
}

// acc = t1: read raw h tile, overwrite slab with relu(t1), acc := h + bB[oi]
__device__ __forceinline__ void transition_(float* AsW, int pr2, int oc,
                                            float (&acc)[8][8], const float (&bbc)[8]) {
#pragma unroll
    for (int oi = 0; oi < 8; ++oi) {
        float* q0 = &AsW[(oc * 8 + oi) * AP_ + ((pr2    ) ^ oc) * 4];
        float* q1 = &AsW[(oc * 8 + oi) * AP_ + ((pr2 + 1) ^ oc) * 4];
        const float4 h0 = *(const float4*)q0;
        const float4 h1 = *(const float4*)q1;
        float4 r0 = {fmaxf(acc[0][oi], 0.f), fmaxf(acc[1][oi], 0.f),
                     fmaxf(acc[2][oi], 0.f), fmaxf(acc[3][oi], 0.f)};
        float4 r1 = {fmaxf(acc[4][oi], 0.f), fmaxf(acc[5][oi], 0.f),
                     fmaxf(acc[6][oi], 0.f), fmaxf(acc[7][oi], 0.f)};
        *(float4*)q0 = r0;
        *(float4*)q1 = r1;
        acc[0][oi] = h0.x + bbc[oi]; acc[1][oi] = h0.y + bbc[oi];
        acc[2][oi] = h0.z + bbc[oi]; acc[3][oi] = h0.w + bbc[oi];
        acc[4][oi] = h1.x + bbc[oi]; acc[5][oi] = h1.y + bbc[oi];
        acc[6][oi] = h1.z + bbc[oi]; acc[7][oi] = h1.w + bbc[oi];
    }
}

__device__ __forceinline__ void load8_(const float* p, float (&d)[8]) {
    const float4 a = *(const float4*)p;
    const float4 b = *(const float4*)(p + 4);
    d[0] = a.x; d[1] = a.y; d[2] = a.z; d[3] = a.w;
    d[4] = b.x; d[5] = b.y; d[6] = b.z; d[7] = b.w;
}

__global__ __launch_bounds__(256, 2) void nsf_kernel(
    const float* __restrict__ x,
    const float* __restrict__ W_in,  const float* __restrict__ b_in,
    const float* __restrict__ b_blk, const float* __restrict__ b_out,
    const float* __restrict__ wt,
    float* __restrict__ out, int n)
{
    // 4 x 16 KB per-wave A-slabs + 16 KB shared weight tile = 80 KB exactly
    __shared__ __align__(16) float As2[WAVES_ * ASZ_];
    __shared__ __align__(16) float Ws[4096];

    const int l    = threadIdx.x;
    const int wave = l >> 6;
    const int wl   = l & 63;
    const int pr   = wl >> 3, oc = wl & 7, pr2 = pr * 2;
    float* AsW = As2 + wave * ASZ_;

    const int gidx = blockIdx.x * (WAVES_ * 64) + l;
    const int idx  = gidx < n ? gidx : (n - 1);

    float z0 = x[3 * idx + 0];
    float z1 = x[3 * idx + 1];
    float z2 = x[3 * idx + 2];
    float lad_total = 0.0f;

    stage_<16>(wt, Ws, wave, wl);   // transform 0, dense tile A0

#pragma unroll 1
    for (int i = 0; i < NT_; ++i) {
        const float ident = z2;
        const float tr0   = z1;
        const float tr1   = z0;

        // ---- h-init -> raw h into A-slab (idents via wave shuffle) ----
        {
            float idp[8], wic[8], bic[8];
#pragma unroll
            for (int t = 0; t < 8; ++t) idp[t] = __shfl(ident, pr * 8 + t, 64);
            load8_(W_in + i * 64 + oc * 8, wic);
            load8_(b_in + i * 64 + oc * 8, bic);
            float hh[8][8];
#pragma unroll
            for (int pi = 0; pi < 8; ++pi)
#pragma unroll
                for (int oi = 0; oi < 8; ++oi)
                    hh[pi][oi] = fmaf(idp[pi], wic[oi], bic[oi]);
            writeA_(AsW, pr2, oc, hh);
        }

        float acc[8][8];

#pragma unroll 1
        for (int j = 0; j < 2; ++j) {
            const int LA = i * 4 + 2 * j;
            float bac[8], bbc[8];
            load8_(b_blk + LA * 64 + oc * 8, bac);
            load8_(b_blk + (LA + 1) * 64 + oc * 8, bbc);

            __syncthreads();                       // dense-A tile ready
#pragma unroll
            for (int pi = 0; pi < 8; ++pi)
#pragma unroll
                for (int oi = 0; oi < 8; ++oi) acc[pi][oi] = bac[oi];
            dense64_<true>(AsW, Ws, pr2, oc, acc); // acc = t1 (relu on A)
            __syncthreads();                       // tile consumed

            stage_<16>(wt + (size_t)(LA + 1) * 4096, Ws, wave, wl);
            transition_(AsW, pr2, oc, acc, bbc);   // slab:=relu(t1), acc:=h+bB
            __syncthreads();                       // dense-B tile ready

            dense64_<false>(AsW, Ws, pr2, oc, acc);// acc = h_new
            __syncthreads();                       // tile consumed

            if (j == 0) {
                stage_<16>(wt + (size_t)(LA + 2) * 4096, Ws, wave, wl);
            } else {
                stage_<10>(wt + WT_BLK_ELEMS + (size_t)(i * 2) * 2560, Ws, wave, wl);
            }
            writeA_(AsW, pr2, oc, acc);            // raw h back to slab
        }

        // ---- output head: two 40-wide halves, raw h operand ----
        float acc30[8][5] = {};
        float acc31[8][5] = {};
        __syncthreads();                           // head half-0 tile ready
        head40_(AsW, Ws, pr2, oc, acc30);
        __syncthreads();
        stage_<10>(wt + WT_BLK_ELEMS + (size_t)(i * 2 + 1) * 2560, Ws, wave, wl);
        __syncthreads();                           // head half-1 tile ready
        head40_(AsW, Ws, pr2, oc, acc31);
        __syncthreads();                           // Ws free for next transform

        if (i < NT_ - 1) stage_<16>(wt + (size_t)((i + 1) * 4) * 4096, Ws, wave, wl);

        // ---- params via per-wave slab (A-slab reused), then splines ----
        const float* bo = b_out + i * 74;
        float y0, l0v, y1, l1v;
        {
#pragma unroll
            for (int pi = 0; pi < 8; ++pi)
#pragma unroll
                for (int m = 0; m < 5; ++m) {
                    const int q = oc + 8 * m;
                    if (q < 37) AsW[(pr * 8 + pi) * PPP_ + q] = acc30[pi][m];
                }
            float p0[37];
#pragma unroll
            for (int q = 0; q < 37; ++q) p0[q] = AsW[wl * PPP_ + q] + bo[q];
            rq_spline_reg(p0, tr0, y0, l0v);
        }
        {
#pragma unroll
            for (int pi = 0; pi < 8; ++pi)
#pragma unroll
                for (int m = 0; m < 5; ++m) {
                    const int q = oc + 8 * m;
                    if (q < 37) AsW[(pr * 8 + pi) * PPP_ + q] = acc31[pi][m];
                }
            float p1[37];
#pragma unroll
            for (int q = 0; q < 37; ++q) p1[q] = AsW[wl * PPP_ + q] + bo[37 + q];
            rq_spline_reg(p1, tr1, y1, l1v);
        }

        lad_total += l0v + l1v;
        z0 = ident;
        z1 = y0;
        z2 = y1;
    }

    if (gidx < n)
        out[gidx] = -0.5f * (z0 * z0 + z1 * z1 + z2 * z2) + LOGZ_ + lad_total;
}

}  // namespace

extern "C" void kernel_launch(void* const* d_in, const int* in_sizes, int n_in,
                              void* d_out, int out_size, void* d_ws, size_t ws_size,
                              hipStream_t stream) {
    const float* x     = (const float*)d_in[0];
    const float* W_in  = (const float*)d_in[1];
    const float* b_in  = (const float*)d_in[2];
    const float* W_blk = (const float*)d_in[3];
    const float* b_blk = (const float*)d_in[4];
    const float* W_out = (const float*)d_in[5];
    const float* b_out = (const float*)d_in[6];
    float* out = (float*)d_out;
    float* wt  = (float*)d_ws;   // 688 KB needed

    const int tot = WT_BLK_ELEMS + WT_OUT_ELEMS;   // 172032
    transpose_k<<<(tot + 255) / 256, 256, 0, stream>>>(W_blk, W_out, wt);

    const int n = in_sizes[0] / 3;
    const int grid = (n + 255) / 256;
    nsf_kernel<<<grid, 256, 0, stream>>>(x, W_in, b_in, b_blk, b_out,
                                         wt, out, n);
}